// Round 4
// baseline (406.179 us; speedup 1.0000x reference)
//
#include <hip/hip_runtime.h>
#include <stdint.h>

#define ENC_D 512
#define ATTN_D 512
#define STR_D 256
#define CELL_D 512
#define BATCH 64
#define SEQ 1024
#define NROWS (BATCH * SEQ)

typedef __bf16 bf16x8 __attribute__((ext_vector_type(8)));
typedef float f32x4 __attribute__((ext_vector_type(4)));

__device__ __forceinline__ unsigned short f2bf(float f) {
    unsigned int u = __float_as_uint(f);
    u += 0x7fffu + ((u >> 16) & 1u);   // RNE
    return (unsigned short)(u >> 16);
}

// ---------------------------------------------------------------------------
// Kernel 1: WF — bf16(W_enc^T) in FRAGMENT-LINEAR order. Granule = 16 B =
// 8 k-elems of one column: for (n, g) with k0 = g*8:
//   nt = n>>4, c = n&15, ks = g>>2, quad = g&3
//   gi = nt*1024 + ks*64 + quad*16 + c       (granule index; byte = gi*16)
// A wave's B-frag load for (nt, ks) at lane = quad*16+c is then contiguous 1 KB.
// LDS tile-transpose: 64 blocks, each does a 64(e) x 64(n) tile.
// ---------------------------------------------------------------------------
__global__ __launch_bounds__(256) void k_prep_wt(const float* __restrict__ W,
                                                 unsigned short* __restrict__ WF) {
    __shared__ unsigned short T[64 * 68];      // [n_local][e_local], stride 68
    const int t = threadIdx.x;
    const int ei = blockIdx.x >> 3, ni = blockIdx.x & 7;
    const int e0 = ei * 64, n0 = ni * 64;

    // load 64x64 tile of W (row-major, coalesced float4), write transposed to LDS
#pragma unroll
    for (int i = 0; i < 4; ++i) {
        const int idx = t + i * 256;           // 0..1023
        const int r = idx >> 4, c4 = idx & 15; // row in tile, float4 col
        const float4 v = *(const float4*)(W + (size_t)(e0 + r) * ATTN_D + n0 + c4 * 4);
        T[(c4 * 4 + 0) * 68 + r] = f2bf(v.x);
        T[(c4 * 4 + 1) * 68 + r] = f2bf(v.y);
        T[(c4 * 4 + 2) * 68 + r] = f2bf(v.z);
        T[(c4 * 4 + 3) * 68 + r] = f2bf(v.w);
    }
    __syncthreads();

    // emit 16 B granules (8 consecutive e for one n) in fragment-linear order
#pragma unroll
    for (int i = 0; i < 2; ++i) {
        const int q = t + i * 256;             // 0..511 granules in this tile
        const int n = q >> 3, ge = q & 7;
        union { unsigned short s[8]; uint4 u; } o;
#pragma unroll
        for (int j = 0; j < 8; ++j) o.s[j] = T[n * 68 + ge * 8 + j];
        const int ng = n0 + n;                 // global column
        const int g = ei * 8 + ge;             // global k-granule (k0 = g*8)
        const int nt = ng >> 4, c = ng & 15;
        const int ks = g >> 2, quad = g & 3;
        const int gi = nt * 1024 + ks * 64 + quad * 16 + c;
        *(uint4*)(WF + (size_t)gi * 8) = o.u;
    }
}

// ---------------------------------------------------------------------------
// Kernel 2: bias[b][a] (fp32). 64 blocks x 256 threads.
// ---------------------------------------------------------------------------
__global__ __launch_bounds__(256) void k_bias(const float* __restrict__ str,
                                              const float* __restrict__ cell,
                                              const float* __restrict__ b_enc,
                                              const float* __restrict__ Wstr,
                                              const float* __restrict__ b_str,
                                              const float* __restrict__ Wcell,
                                              const float* __restrict__ b_cell,
                                              float* __restrict__ bias) {
    __shared__ float sj[768];
    __shared__ f32x4 red[128];
    const int b = blockIdx.x, t = threadIdx.x;
#pragma unroll
    for (int i = 0; i < 3; ++i) {
        const int idx = t + i * 256;
        sj[idx] = (idx < 256) ? str[b * STR_D + idx] : cell[b * CELL_D + idx - 256];
    }
    __syncthreads();

    const int a4 = t & 127, jh = t >> 7;   // jh wave-uniform (waves 0,1 vs 2,3)
    f32x4 acc = {0.f, 0.f, 0.f, 0.f};
    if (jh == 0) {
#pragma unroll 8
        for (int j = 0; j < 256; ++j) {
            const float s = sj[j];
            const float4 wv = *(const float4*)(Wstr + (size_t)j * ATTN_D + a4 * 4);
            acc[0] += s * wv.x; acc[1] += s * wv.y; acc[2] += s * wv.z; acc[3] += s * wv.w;
        }
#pragma unroll 8
        for (int j = 0; j < 128; ++j) {
            const float s = sj[256 + j];
            const float4 wv = *(const float4*)(Wcell + (size_t)j * ATTN_D + a4 * 4);
            acc[0] += s * wv.x; acc[1] += s * wv.y; acc[2] += s * wv.z; acc[3] += s * wv.w;
        }
    } else {
#pragma unroll 8
        for (int j = 128; j < 512; ++j) {
            const float s = sj[256 + j];
            const float4 wv = *(const float4*)(Wcell + (size_t)j * ATTN_D + a4 * 4);
            acc[0] += s * wv.x; acc[1] += s * wv.y; acc[2] += s * wv.z; acc[3] += s * wv.w;
        }
        red[a4] = acc;
    }
    __syncthreads();
    if (jh == 0) {
        const f32x4 o = red[a4];
        const int a = a4 * 4;
        const float4 be = *(const float4*)(b_enc + a);
        const float4 bs = *(const float4*)(b_str + a);
        const float4 bc = *(const float4*)(b_cell + a);
        f32x4 r;
        r[0] = acc[0] + o[0] + be.x + bs.x + bc.x;
        r[1] = acc[1] + o[1] + be.y + bs.y + bc.y;
        r[2] = acc[2] + o[2] + be.z + bs.z + bc.z;
        r[3] = acc[3] + o[3] + be.w + bs.w + bc.w;
        *(f32x4*)(bias + b * ATTN_D + a) = r;
    }
}

// ---------------------------------------------------------------------------
// Kernel 3: fused scores GEMM — barrier-free, LDS-free.
// Grid 2048 x 64 threads (1 wave). Wave owns 32 rows: A in regs (128 VGPR).
// B-frags stream from L2 in fragment-linear layout: one coalesced 1 KB
// global_load_dwordx4 per k-slice feeds 2 MFMAs; no __syncthreads anywhere,
// compiler pipelines loads with fine-grained vmcnt.
// ---------------------------------------------------------------------------
__global__ __launch_bounds__(64) void k_scores(const float* __restrict__ E,
                                               const unsigned short* __restrict__ WF,
                                               const float* __restrict__ bias,
                                               const float* __restrict__ Wcomb,
                                               float* __restrict__ scores) {
    const int lane = threadIdx.x;
    const int quad = lane >> 4, c = lane & 15;
    const int r0 = blockIdx.x * 32;
    const int b = blockIdx.x >> 5;             // 32 blocks per batch

    // ---- load A: 2 M-tiles x full K in registers (E read exactly once) ----
    bf16x8 afr[2][16];
#pragma unroll
    for (int m = 0; m < 2; ++m) {
        const float* Ep = E + (size_t)(r0 + m * 16 + c) * ENC_D + quad * 8;
#pragma unroll
        for (int ks = 0; ks < 16; ++ks) {
            const float4 v0 = *(const float4*)(Ep + ks * 32);
            const float4 v1 = *(const float4*)(Ep + ks * 32 + 4);
            union { unsigned short s[8]; bf16x8 v; } u;
            u.s[0] = f2bf(v0.x); u.s[1] = f2bf(v0.y);
            u.s[2] = f2bf(v0.z); u.s[3] = f2bf(v0.w);
            u.s[4] = f2bf(v1.x); u.s[5] = f2bf(v1.y);
            u.s[6] = f2bf(v1.z); u.s[7] = f2bf(v1.w);
            afr[m][ks] = u.v;
        }
    }

    float sc0[4] = {0.f, 0.f, 0.f, 0.f};
    float sc1[4] = {0.f, 0.f, 0.f, 0.f};
    const float* biasb = bias + b * ATTN_D;

    for (int nt = 0; nt < 32; ++nt) {
        const unsigned short* wp = WF + (size_t)(nt * 1024 + lane) * 8;
        f32x4 a0 = {0.f, 0.f, 0.f, 0.f}, a1 = {0.f, 0.f, 0.f, 0.f};
#pragma unroll
        for (int ks = 0; ks < 16; ++ks) {
            const bf16x8 bf = *(const bf16x8*)(wp + ks * 512);   // 64 granules * 8
            a0 = __builtin_amdgcn_mfma_f32_16x16x32_bf16(afr[0][ks], bf, a0, 0, 0, 0);
            a1 = __builtin_amdgcn_mfma_f32_16x16x32_bf16(afr[1][ks], bf, a1, 0, 0, 0);
        }
        const int n = nt * 16 + c;
        const float bi = biasb[n], wc = Wcomb[n];
#pragma unroll
        for (int r = 0; r < 4; ++r) {
            float v;
            v = a0[r] + bi; sc0[r] += (v > 0.f ? v : 0.f) * wc;
            v = a1[r] + bi; sc1[r] += (v > 0.f ? v : 0.f) * wc;
        }
    }

    // reduce across the 16 column-lanes
#pragma unroll
    for (int r = 0; r < 4; ++r) {
        float v0 = sc0[r], v1 = sc1[r];
        v0 += __shfl_xor(v0, 1); v1 += __shfl_xor(v1, 1);
        v0 += __shfl_xor(v0, 2); v1 += __shfl_xor(v1, 2);
        v0 += __shfl_xor(v0, 4); v1 += __shfl_xor(v1, 4);
        sc0[r] = v0 + __shfl_xor(v0, 8);
        sc1[r] = v1 + __shfl_xor(v1, 8);
    }
    if (c == 0) {
        const int g0 = r0 + quad * 4;
#pragma unroll
        for (int r = 0; r < 4; ++r) scores[g0 + r] = sc0[r];
#pragma unroll
        for (int r = 0; r < 4; ++r) scores[g0 + 16 + r] = sc1[r];
    }
}

// ---------------------------------------------------------------------------
// Kernel 4: softmax over L=1024 per batch (in place)
// ---------------------------------------------------------------------------
__global__ __launch_bounds__(256) void k_softmax(float* __restrict__ s) {
    __shared__ float red[256];
    const int b = blockIdx.x, t = threadIdx.x;
    float v[4];
    float m = -1e30f;
#pragma unroll
    for (int i = 0; i < 4; ++i) {
        v[i] = s[b * SEQ + i * 256 + t];
        m = fmaxf(m, v[i]);
    }
    red[t] = m;
    __syncthreads();
    for (int o = 128; o > 0; o >>= 1) {
        if (t < o) red[t] = fmaxf(red[t], red[t + o]);
        __syncthreads();
    }
    m = red[0];
    __syncthreads();
    float sum = 0.f;
#pragma unroll
    for (int i = 0; i < 4; ++i) {
        v[i] = __expf(v[i] - m);
        sum += v[i];
    }
    red[t] = sum;
    __syncthreads();
    for (int o = 128; o > 0; o >>= 1) {
        if (t < o) red[t] += red[t + o];
        __syncthreads();
    }
    const float inv = 1.f / red[0];
#pragma unroll
    for (int i = 0; i < 4; ++i) s[b * SEQ + i * 256 + t] = v[i] * inv;
}

// ---------------------------------------------------------------------------
// Kernel 5: context partials. 1024 blocks x 128 threads, 64 L-rows per block.
// ---------------------------------------------------------------------------
__global__ __launch_bounds__(128) void k_context(const float* __restrict__ E,
                                                 const float* __restrict__ wts,
                                                 float* __restrict__ part) {
    __shared__ float wl[64];
    const int blk = blockIdx.x, t = threadIdx.x;
    const int b = blk >> 4, lo = blk & 15;
    if (t < 64) wl[t] = wts[b * SEQ + lo * 64 + t];
    __syncthreads();
    const float* Ep = E + ((size_t)(b * SEQ + lo * 64)) * ENC_D + t * 4;
    f32x4 acc = {0.f, 0.f, 0.f, 0.f};
#pragma unroll 8
    for (int l = 0; l < 64; ++l) {
        const float4 v = *(const float4*)(Ep + (size_t)l * ENC_D);
        const float wv = wl[l];
        acc[0] += wv * v.x; acc[1] += wv * v.y;
        acc[2] += wv * v.z; acc[3] += wv * v.w;
    }
    *(f32x4*)(&part[(size_t)(b * 16 + lo) * ENC_D + t * 4]) = acc;
}

// ---------------------------------------------------------------------------
// Kernel 6: reduce 16 L-chunk partials -> out[b][e]
// ---------------------------------------------------------------------------
__global__ __launch_bounds__(256) void k_reduce(const float* __restrict__ part,
                                                float* __restrict__ out) {
    const int idx = blockIdx.x * 256 + threadIdx.x;  // 0..32767
    const int b = idx >> 9, e = idx & 511;
    const float* p = part + (size_t)b * 16 * ENC_D + e;
    float s = 0.f;
#pragma unroll
    for (int i = 0; i < 16; ++i) s += p[i * ENC_D];
    out[idx] = s;
}

// ---------------------------------------------------------------------------
extern "C" void kernel_launch(void* const* d_in, const int* in_sizes, int n_in,
                              void* d_out, int out_size, void* d_ws, size_t ws_size,
                              hipStream_t stream) {
    const float* E      = (const float*)d_in[0];
    const float* str    = (const float*)d_in[1];
    const float* cell   = (const float*)d_in[2];
    const float* Wenc   = (const float*)d_in[3];
    const float* b_enc  = (const float*)d_in[4];
    const float* Wstr   = (const float*)d_in[5];
    const float* b_str  = (const float*)d_in[6];
    const float* Wcell  = (const float*)d_in[7];
    const float* b_cell = (const float*)d_in[8];
    const float* Wcomb  = (const float*)d_in[9];
    // d_in[10] = b_comb: uniform pre-softmax shift — no effect, skipped.
    float* out = (float*)d_out;

    char* ws = (char*)d_ws;
    unsigned short* WF = (unsigned short*)ws;                 // 512 KB (frag-linear)
    float* bias   = (float*)(ws + (512 << 10));               // 128 KB
    float* scores = (float*)(ws + (512 << 10) + (128 << 10)); // 256 KB
    float* part   = (float*)(ws + (512 << 10) + (128 << 10) + (256 << 10)); // 2 MB

    k_prep_wt<<<64, 256, 0, stream>>>(Wenc, WF);
    k_bias<<<64, 256, 0, stream>>>(str, cell, b_enc, Wstr, b_str, Wcell, b_cell, bias);
    k_scores<<<NROWS / 32, 64, 0, stream>>>(E, WF, bias, Wcomb, scores);
    k_softmax<<<BATCH, 256, 0, stream>>>(scores);
    k_context<<<1024, 128, 0, stream>>>(E, scores, part);
    k_reduce<<<NROWS / 512, 256, 0, stream>>>(part, out);
}

// Round 5
// 284.351 us; speedup vs baseline: 1.4284x; 1.4284x over previous
//
#include <hip/hip_runtime.h>
#include <stdint.h>

#define ENC_D 512
#define ATTN_D 512
#define STR_D 256
#define CELL_D 512
#define BATCH 64
#define SEQ 1024
#define NROWS (BATCH * SEQ)

typedef __bf16 bf16x8 __attribute__((ext_vector_type(8)));
typedef float f32x4 __attribute__((ext_vector_type(4)));

__device__ __forceinline__ unsigned short f2bf(float f) {
    unsigned int u = __float_as_uint(f);
    u += 0x7fffu + ((u >> 16) & 1u);   // RNE
    return (unsigned short)(u >> 16);
}

__device__ __forceinline__ void lds_cp16(void* l, const void* g) {
    __builtin_amdgcn_global_load_lds(
        (const __attribute__((address_space(1))) unsigned int*)g,
        (__attribute__((address_space(3))) unsigned int*)l, 16, 0, 0);
}

// ---------------------------------------------------------------------------
// Kernel 1: WF — bf16(W_enc^T) in FRAGMENT-LINEAR order (as round 4):
//   granule (16 B) = 8 k-elems of one column; gi = nt*1024 + ks*64 + quad*16 + c
// A 32-col chunk (2 nt) is a contiguous 32 KB slab; a flat copy into LDS gives
// conflict-free lane-linear ds_read_b128 fragments.
// ---------------------------------------------------------------------------
__global__ __launch_bounds__(256) void k_prep_wt(const float* __restrict__ W,
                                                 unsigned short* __restrict__ WF) {
    __shared__ unsigned short T[64 * 68];      // [n_local][e_local], stride 68
    const int t = threadIdx.x;
    const int ei = blockIdx.x >> 3, ni = blockIdx.x & 7;
    const int e0 = ei * 64, n0 = ni * 64;

#pragma unroll
    for (int i = 0; i < 4; ++i) {
        const int idx = t + i * 256;           // 0..1023
        const int r = idx >> 4, c4 = idx & 15;
        const float4 v = *(const float4*)(W + (size_t)(e0 + r) * ATTN_D + n0 + c4 * 4);
        T[(c4 * 4 + 0) * 68 + r] = f2bf(v.x);
        T[(c4 * 4 + 1) * 68 + r] = f2bf(v.y);
        T[(c4 * 4 + 2) * 68 + r] = f2bf(v.z);
        T[(c4 * 4 + 3) * 68 + r] = f2bf(v.w);
    }
    __syncthreads();

#pragma unroll
    for (int i = 0; i < 2; ++i) {
        const int q = t + i * 256;             // 0..511 granules in this tile
        const int n = q >> 3, ge = q & 7;
        union { unsigned short s[8]; uint4 u; } o;
#pragma unroll
        for (int j = 0; j < 8; ++j) o.s[j] = T[n * 68 + ge * 8 + j];
        const int ng = n0 + n;                 // global column
        const int g = ei * 8 + ge;             // global k-granule (k0 = g*8)
        const int nt = ng >> 4, c = ng & 15;
        const int ks = g >> 2, quad = g & 3;
        const int gi = nt * 1024 + ks * 64 + quad * 16 + c;
        *(uint4*)(WF + (size_t)gi * 8) = o.u;
    }
}

// ---------------------------------------------------------------------------
// Kernel 2a: bias partials. grid (12, 64): jq = 64-row slice of the 768
// combined (str|cell) rows, b = batch. 128 threads, one float4 col each.
// part layout: [jq][b][a]  (reuses the k_context 'part' scratch — k_context
// runs later in the stream).
// ---------------------------------------------------------------------------
__global__ __launch_bounds__(128) void k_bias_part(const float* __restrict__ str,
                                                   const float* __restrict__ cell,
                                                   const float* __restrict__ Wstr,
                                                   const float* __restrict__ Wcell,
                                                   float* __restrict__ part) {
    __shared__ float sj[64];
    const int jq = blockIdx.x, b = blockIdx.y, t = threadIdx.x;
    const float* hvec;
    const float* Wrow;
    if (jq < 4) { hvec = str + b * STR_D + jq * 64;            Wrow = Wstr + (size_t)(jq * 64) * ATTN_D; }
    else        { hvec = cell + b * CELL_D + (jq - 4) * 64;    Wrow = Wcell + (size_t)((jq - 4) * 64) * ATTN_D; }
    if (t < 64) sj[t] = hvec[t];
    __syncthreads();

    f32x4 acc = {0.f, 0.f, 0.f, 0.f};
#pragma unroll 8
    for (int i = 0; i < 64; ++i) {
        const float s = sj[i];
        const float4 wv = *(const float4*)(Wrow + (size_t)i * ATTN_D + t * 4);
        acc[0] += s * wv.x; acc[1] += s * wv.y; acc[2] += s * wv.z; acc[3] += s * wv.w;
    }
    *(f32x4*)(part + (size_t)(jq * BATCH + b) * ATTN_D + t * 4) = acc;
}

// ---------------------------------------------------------------------------
// Kernel 2b: bias finalize: bias[b][a] = sum_jq part + b_enc + b_str + b_cell
// ---------------------------------------------------------------------------
__global__ __launch_bounds__(256) void k_bias_fin(const float* __restrict__ part,
                                                  const float* __restrict__ b_enc,
                                                  const float* __restrict__ b_str,
                                                  const float* __restrict__ b_cell,
                                                  float* __restrict__ bias) {
    const int idx = blockIdx.x * 256 + threadIdx.x;  // 0..32767
    const int b = idx >> 9, a = idx & 511;
    float s = b_enc[a] + b_str[a] + b_cell[a];
#pragma unroll
    for (int jq = 0; jq < 12; ++jq)
        s += part[(size_t)(jq * BATCH + b) * ATTN_D + a];
    bias[idx] = s;
}

// ---------------------------------------------------------------------------
// Kernel 3: fused scores GEMM. 512 blocks x 256 threads (4 waves), M=128/block.
// Wave owns 32 rows (A in regs, 128 VGPR). B double-buffered in LDS via flat
// async copy of fragment-linear WF (32-col chunks, 2x32 KB); ds_read_b128
// fragments are lane-linear 16 B stride -> zero bank conflicts.
// ---------------------------------------------------------------------------
__global__ __launch_bounds__(256, 3) void k_scores(const float* __restrict__ E,
                                                   const unsigned short* __restrict__ WF,
                                                   const float* __restrict__ bias,
                                                   const float* __restrict__ Wcomb,
                                                   float* __restrict__ scores) {
    __shared__ unsigned short buf[2][16384];    // 2 x 32 KB

    const int tid = threadIdx.x;
    const int r0 = blockIdx.x * 128;
    const int b = blockIdx.x >> 3;              // 8 blocks per batch
    const int w = tid >> 6, lane = tid & 63;
    const int quad = lane >> 4, c = lane & 15;

    // stage chunk 0 (async, 32 KB = 8 issues x 256 thr x 16 B)
#pragma unroll
    for (int i = 0; i < 8; ++i)
        lds_cp16((char*)&buf[0][0] + i * 4096 + tid * 16,
                 (const char*)WF + i * 4096 + tid * 16);

    // load A: 2 M-tiles x full K in registers (E read exactly once)
    bf16x8 afr[2][16];
#pragma unroll
    for (int m = 0; m < 2; ++m) {
        const float* Ep = E + (size_t)(r0 + w * 32 + m * 16 + c) * ENC_D + quad * 8;
#pragma unroll
        for (int ks = 0; ks < 16; ++ks) {
            const float4 v0 = *(const float4*)(Ep + ks * 32);
            const float4 v1 = *(const float4*)(Ep + ks * 32 + 4);
            union { unsigned short s[8]; bf16x8 v; } u;
            u.s[0] = f2bf(v0.x); u.s[1] = f2bf(v0.y);
            u.s[2] = f2bf(v0.z); u.s[3] = f2bf(v0.w);
            u.s[4] = f2bf(v1.x); u.s[5] = f2bf(v1.y);
            u.s[6] = f2bf(v1.z); u.s[7] = f2bf(v1.w);
            afr[m][ks] = u.v;
        }
    }

    float sc0[4] = {0.f, 0.f, 0.f, 0.f};
    float sc1[4] = {0.f, 0.f, 0.f, 0.f};
    const float* biasb = bias + b * ATTN_D;

    __syncthreads();   // chunk 0 staged

    for (int ch = 0; ch < 16; ++ch) {
        if (ch < 15) {
            const char* gsrc = (const char*)WF + (size_t)(ch + 1) * 32768;
            char* ldst = (char*)&buf[(ch + 1) & 1][0];
#pragma unroll
            for (int i = 0; i < 8; ++i)
                lds_cp16(ldst + i * 4096 + tid * 16, gsrc + i * 4096 + tid * 16);
        }

        const unsigned short* wb = &buf[ch & 1][0];
        f32x4 a00 = {0.f,0.f,0.f,0.f}, a01 = {0.f,0.f,0.f,0.f};
        f32x4 a10 = {0.f,0.f,0.f,0.f}, a11 = {0.f,0.f,0.f,0.f};
#pragma unroll
        for (int ks = 0; ks < 16; ++ks) {
            const bf16x8 b0 = *(const bf16x8*)(wb + (ks * 64 + lane) * 8);
            const bf16x8 b1 = *(const bf16x8*)(wb + 8192 + (ks * 64 + lane) * 8);
            a00 = __builtin_amdgcn_mfma_f32_16x16x32_bf16(afr[0][ks], b0, a00, 0, 0, 0);
            a10 = __builtin_amdgcn_mfma_f32_16x16x32_bf16(afr[1][ks], b0, a10, 0, 0, 0);
            a01 = __builtin_amdgcn_mfma_f32_16x16x32_bf16(afr[0][ks], b1, a01, 0, 0, 0);
            a11 = __builtin_amdgcn_mfma_f32_16x16x32_bf16(afr[1][ks], b1, a11, 0, 0, 0);
        }

        const int n0 = ch * 32 + c;
        const float bi0 = biasb[n0], wc0 = Wcomb[n0];
        const float bi1 = biasb[n0 + 16], wc1 = Wcomb[n0 + 16];
#pragma unroll
        for (int r = 0; r < 4; ++r) {
            float v;
            v = a00[r] + bi0; sc0[r] += (v > 0.f ? v : 0.f) * wc0;
            v = a01[r] + bi1; sc0[r] += (v > 0.f ? v : 0.f) * wc1;
            v = a10[r] + bi0; sc1[r] += (v > 0.f ? v : 0.f) * wc0;
            v = a11[r] + bi1; sc1[r] += (v > 0.f ? v : 0.f) * wc1;
        }
        __syncthreads();
    }

    // reduce across the 16 column-lanes
#pragma unroll
    for (int r = 0; r < 4; ++r) {
        float v0 = sc0[r], v1 = sc1[r];
        v0 += __shfl_xor(v0, 1); v1 += __shfl_xor(v1, 1);
        v0 += __shfl_xor(v0, 2); v1 += __shfl_xor(v1, 2);
        v0 += __shfl_xor(v0, 4); v1 += __shfl_xor(v1, 4);
        sc0[r] = v0 + __shfl_xor(v0, 8);
        sc1[r] = v1 + __shfl_xor(v1, 8);
    }
    if (c == 0) {
        const int g0 = r0 + w * 32 + quad * 4;
#pragma unroll
        for (int r = 0; r < 4; ++r) scores[g0 + r] = sc0[r];
#pragma unroll
        for (int r = 0; r < 4; ++r) scores[g0 + 16 + r] = sc1[r];
    }
}

// ---------------------------------------------------------------------------
// Kernel 4: softmax over L=1024 per batch (in place)
// ---------------------------------------------------------------------------
__global__ __launch_bounds__(256) void k_softmax(float* __restrict__ s) {
    __shared__ float red[256];
    const int b = blockIdx.x, t = threadIdx.x;
    float v[4];
    float m = -1e30f;
#pragma unroll
    for (int i = 0; i < 4; ++i) {
        v[i] = s[b * SEQ + i * 256 + t];
        m = fmaxf(m, v[i]);
    }
    red[t] = m;
    __syncthreads();
    for (int o = 128; o > 0; o >>= 1) {
        if (t < o) red[t] = fmaxf(red[t], red[t + o]);
        __syncthreads();
    }
    m = red[0];
    __syncthreads();
    float sum = 0.f;
#pragma unroll
    for (int i = 0; i < 4; ++i) {
        v[i] = __expf(v[i] - m);
        sum += v[i];
    }
    red[t] = sum;
    __syncthreads();
    for (int o = 128; o > 0; o >>= 1) {
        if (t < o) red[t] += red[t + o];
        __syncthreads();
    }
    const float inv = 1.f / red[0];
#pragma unroll
    for (int i = 0; i < 4; ++i) s[b * SEQ + i * 256 + t] = v[i] * inv;
}

// ---------------------------------------------------------------------------
// Kernel 5: context partials. 1024 blocks x 128 threads, 64 L-rows per block.
// ---------------------------------------------------------------------------
__global__ __launch_bounds__(128) void k_context(const float* __restrict__ E,
                                                 const float* __restrict__ wts,
                                                 float* __restrict__ part) {
    __shared__ float wl[64];
    const int blk = blockIdx.x, t = threadIdx.x;
    const int b = blk >> 4, lo = blk & 15;
    if (t < 64) wl[t] = wts[b * SEQ + lo * 64 + t];
    __syncthreads();
    const float* Ep = E + ((size_t)(b * SEQ + lo * 64)) * ENC_D + t * 4;
    f32x4 acc = {0.f, 0.f, 0.f, 0.f};
#pragma unroll 8
    for (int l = 0; l < 64; ++l) {
        const float4 v = *(const float4*)(Ep + (size_t)l * ENC_D);
        const float wv = wl[l];
        acc[0] += wv * v.x; acc[1] += wv * v.y;
        acc[2] += wv * v.z; acc[3] += wv * v.w;
    }
    *(f32x4*)(&part[(size_t)(b * 16 + lo) * ENC_D + t * 4]) = acc;
}

// ---------------------------------------------------------------------------
// Kernel 6: reduce 16 L-chunk partials -> out[b][e]
// ---------------------------------------------------------------------------
__global__ __launch_bounds__(256) void k_reduce(const float* __restrict__ part,
                                                float* __restrict__ out) {
    const int idx = blockIdx.x * 256 + threadIdx.x;  // 0..32767
    const int b = idx >> 9, e = idx & 511;
    const float* p = part + (size_t)b * 16 * ENC_D + e;
    float s = 0.f;
#pragma unroll
    for (int i = 0; i < 16; ++i) s += p[i * ENC_D];
    out[idx] = s;
}

// ---------------------------------------------------------------------------
extern "C" void kernel_launch(void* const* d_in, const int* in_sizes, int n_in,
                              void* d_out, int out_size, void* d_ws, size_t ws_size,
                              hipStream_t stream) {
    const float* E      = (const float*)d_in[0];
    const float* str    = (const float*)d_in[1];
    const float* cell   = (const float*)d_in[2];
    const float* Wenc   = (const float*)d_in[3];
    const float* b_enc  = (const float*)d_in[4];
    const float* Wstr   = (const float*)d_in[5];
    const float* b_str  = (const float*)d_in[6];
    const float* Wcell  = (const float*)d_in[7];
    const float* b_cell = (const float*)d_in[8];
    const float* Wcomb  = (const float*)d_in[9];
    // d_in[10] = b_comb: uniform pre-softmax shift — no effect, skipped.
    float* out = (float*)d_out;

    char* ws = (char*)d_ws;
    unsigned short* WF = (unsigned short*)ws;                 // 512 KB (frag-linear)
    float* bias   = (float*)(ws + (512 << 10));               // 128 KB
    float* scores = (float*)(ws + (512 << 10) + (128 << 10)); // 256 KB
    float* part   = (float*)(ws + (512 << 10) + (128 << 10) + (256 << 10)); // 2 MB
    // bias partials reuse 'part' (k_context runs later in the stream)
    float* bpart  = part;   // 12*64*512*4 = 1.5 MB <= 2 MB

    k_prep_wt<<<64, 256, 0, stream>>>(Wenc, WF);
    k_bias_part<<<dim3(12, 64), 128, 0, stream>>>(str, cell, Wstr, Wcell, bpart);
    k_bias_fin<<<128, 256, 0, stream>>>(bpart, b_enc, b_str, b_cell, bias);
    k_scores<<<NROWS / 128, 256, 0, stream>>>(E, WF, bias, Wcomb, scores);
    k_softmax<<<BATCH, 256, 0, stream>>>(scores);
    k_context<<<1024, 128, 0, stream>>>(E, scores, part);
    k_reduce<<<NROWS / 512, 256, 0, stream>>>(part, out);
}